// Round 1
// baseline (343.190 us; speedup 1.0000x reference)
//
#include <hip/hip_runtime.h>
#include <math.h>

#define BB 2
#define TT 2048
#define DD 2048
#define HH 16
#define KVHN 4
#define HDIM 128
#define NKV 3072   // packed q|k|v row width

typedef unsigned short u16;
typedef unsigned int u32;
typedef __bf16 bf16x8 __attribute__((ext_vector_type(8)));
typedef float  f32x4  __attribute__((ext_vector_type(4)));

#define AS1 __attribute__((address_space(1)))
#define AS3 __attribute__((address_space(3)))

__device__ __forceinline__ void dma16(const u16* g, u16* l) {
  __builtin_amdgcn_global_load_lds((const AS1 u32*)g, (AS3 u32*)l, 16, 0, 0);
}

__device__ __forceinline__ u16 f2bf(float f) {
  u32 u = __float_as_uint(f);
  u32 r = (u + 0x7FFFu + ((u >> 16) & 1u)) >> 16;
  return (u16)r;
}
__device__ __forceinline__ float bf2f(u32 h) { return __uint_as_float(h << 16); }

__device__ __forceinline__ u32 pack2(float a, float b) {
  union { __bf16 h[2]; u32 u; } cv;
  cv.h[0] = (__bf16)a; cv.h[1] = (__bf16)b;
  return cv.u;
}

// ---------------- cast fp32 -> bf16 ----------------------------------------
__global__ __launch_bounds__(256) void castf2b(const float* __restrict__ in,
                                               u16* __restrict__ out) {
  size_t i4 = (size_t)blockIdx.x * 256 + threadIdx.x;
  float4 v = *(const float4*)(in + i4 * 4);
  ushort4 o;
  o.x = f2bf(v.x); o.y = f2bf(v.y); o.z = f2bf(v.z); o.w = f2bf(v.w);
  *(ushort4*)(out + i4 * 4) = o;
}

// ---------------- transpose + cast: W[K][N] fp32 -> WT[N][K] bf16 ----------
__global__ __launch_bounds__(256) void tcast(const float* __restrict__ W,
                                             u16* __restrict__ WT,
                                             int K, int N) {
  __shared__ float tile[32][33];
  const int n0 = blockIdx.x * 32, k0 = blockIdx.y * 32;
  const int r = threadIdx.x >> 3;
  const int c4 = (threadIdx.x & 7) * 4;
  float4 v = *(const float4*)(W + (size_t)(k0 + r) * N + n0 + c4);
  tile[r][c4 + 0] = v.x; tile[r][c4 + 1] = v.y;
  tile[r][c4 + 2] = v.z; tile[r][c4 + 3] = v.w;
  __syncthreads();
  ushort4 o;
  o.x = f2bf(tile[c4 + 0][r]); o.y = f2bf(tile[c4 + 1][r]);
  o.z = f2bf(tile[c4 + 2][r]); o.w = f2bf(tile[c4 + 3][r]);
  *(ushort4*)(WT + (size_t)(n0 + r) * K + k0 + c4) = o;
}

// ---------------- m97-style MFMA GEMM: C = A @ BT^T ------------------------
template <int OUT_BF16>
__global__ __launch_bounds__(256) void gemm2(const u16* __restrict__ A,
                                             const u16* __restrict__ BT,
                                             void* __restrict__ Cv,
                                             int N, int K) {
  __shared__ u16 As[128 * 32];
  __shared__ u16 Bs[128 * 32];
  const int t = threadIdx.x;
  const int l = t & 63, w = t >> 6;
  const int lm = l & 15, quad = l >> 4;
  const int wm = w & 1, wn = w >> 1;
  const int m0 = blockIdx.y * 128, n0 = blockIdx.x * 128;
  const int wu = __builtin_amdgcn_readfirstlane(w);

  f32x4 acc[4][4];
  #pragma unroll
  for (int i = 0; i < 4; ++i)
    #pragma unroll
    for (int j = 0; j < 4; ++j) acc[i][j] = (f32x4){0.f, 0.f, 0.f, 0.f};

  for (int k0 = 0; k0 < K; k0 += 32) {
    __syncthreads();
    #pragma unroll
    for (int i = 0; i < 2; ++i) {
      int p0 = (wu * 2 + i) * 64;
      int p = p0 + l;
      int row = p >> 2, c = p & 3;
      dma16(A  + (size_t)(m0 + row) * K + k0 + c * 8, &As[p0 * 8]);
      dma16(BT + (size_t)(n0 + row) * K + k0 + c * 8, &Bs[p0 * 8]);
    }
    __syncthreads();
    bf16x8 a[4], bq[4];
    #pragma unroll
    for (int i = 0; i < 4; ++i)
      a[i] = *(const bf16x8*)&As[(wm * 64 + i * 16 + lm) * 32 + quad * 8];
    #pragma unroll
    for (int j = 0; j < 4; ++j)
      bq[j] = *(const bf16x8*)&Bs[(wn * 64 + j * 16 + lm) * 32 + quad * 8];
    #pragma unroll
    for (int i = 0; i < 4; ++i)
      #pragma unroll
      for (int j = 0; j < 4; ++j)
        acc[i][j] = __builtin_amdgcn_mfma_f32_16x16x32_bf16(a[i], bq[j], acc[i][j], 0, 0, 0);
  }

  #pragma unroll
  for (int i = 0; i < 4; ++i) {
    #pragma unroll
    for (int r = 0; r < 4; ++r) {
      size_t gr = (size_t)(m0 + wm * 64 + i * 16 + quad * 4 + r);
      #pragma unroll
      for (int j = 0; j < 4; ++j) {
        int gc = n0 + wn * 64 + j * 16 + lm;
        if (OUT_BF16) ((u16*)Cv)[gr * N + gc] = f2bf(acc[i][j][r]);
        else          ((float*)Cv)[gr * N + gc] = acc[i][j][r];
      }
    }
  }
}

// ---------------- RoPE in-place on packed QKV rows (q scaled) --------------
__global__ __launch_bounds__(256) void rope2(u16* p) {
  const int row = blockIdx.x;
  const int pos = row & (TT - 1);
  u16* base = p + (size_t)row * NKV;
  float e0[5], e1[5];
  #pragma unroll
  for (int i = 0; i < 5; ++i) {
    int item = threadIdx.x + i * 256;
    int h20 = item >> 6, f = item & 63;
    int col = (h20 < 16) ? h20 * 128 : 2048 + (h20 - 16) * 128;
    u32 u = *(const u32*)(base + col + 2 * f);
    e0[i] = bf2f(u & 0xffffu);
    e1[i] = bf2f(u >> 16);
  }
  __syncthreads();
  #pragma unroll
  for (int i = 0; i < 5; ++i) {
    int item = threadIdx.x + i * 256;
    int h20 = item >> 6, f = item & 63;
    int col = (h20 < 16) ? h20 * 128 : 2048 + (h20 - 16) * 128;
    float sc = (h20 < 16) ? 0.08838834764831845f : 1.0f;
    float inv = exp2f((float)f * -0.20762050593046898f);  // 10000^(-f/64)
    float ang = (float)pos * inv;
    float sn, cs;
    sincosf(ang, &sn, &cs);
    base[col + f]      = f2bf((e0[i] * cs - e1[i] * sn) * sc);
    base[col + 64 + f] = f2bf((e0[i] * sn + e1[i] * cs) * sc);
  }
}

// ---------------- V transpose: QKV v-part -> Vt[(b*4+vh)*128+d][T] ---------
__global__ __launch_bounds__(256) void vtrans(const u16* __restrict__ QKV,
                                              u16* __restrict__ Vt) {
  __shared__ u16 tl[64][72];
  const int t0 = blockIdx.x * 64;
  const int y  = blockIdx.y;        // 0..7
  const int b  = blockIdx.z;
  #pragma unroll
  for (int i = 0; i < 2; ++i) {
    int idx = threadIdx.x + i * 256;
    int r = idx >> 3, c = (idx & 7) * 8;
    *(uint4*)&tl[r][c] =
        *(const uint4*)(QKV + (size_t)(b * TT + t0 + r) * NKV + 2560 + y * 64 + c);
  }
  __syncthreads();
  const int vh = y >> 1;
  #pragma unroll
  for (int i = 0; i < 2; ++i) {
    int idx = threadIdx.x + i * 256;
    int dr = idx >> 3, tc = (idx & 7) * 8;
    u16 tmp[8];
    #pragma unroll
    for (int j = 0; j < 8; ++j) tmp[j] = tl[tc + j][dr];
    int dloc = (y & 1) * 64 + dr;
    *(uint4*)(Vt + (size_t)((b * KVHN + vh) * HDIM + dloc) * TT + t0 + tc) =
        *(const uint4*)tmp;
  }
}

// ---------------- MFMA flash attention v3 ----------------------------------
// One 64-row q-tile per block (grid.x=32 -> 1024 blocks, 4/CU), KVBLK=32,
// LDS 36KB, defer-max softmax, setprio MFMA clusters, hoisted stage pointers.
__global__ __launch_bounds__(256, 4) void attn3(const u16* __restrict__ QKV,
                                                const u16* __restrict__ Vt,
                                                u16* __restrict__ Ob) {
  __shared__ u16 KsA[32 * 128], KsB[32 * 128];
  __shared__ u16 VsA[128 * 32], VsB[128 * 32];
  __shared__ u16 Pw[4 * 512];
  const int t = threadIdx.x;
  const int l = t & 63, w = t >> 6;
  const int lm = l & 15, quad = l >> 4;
  const int h = blockIdx.y, b = blockIdx.z;
  // complement-pair qt swizzle: blocks (x,y) and (x,y+8) share a CU (ids
  // differ by 256); give them q-tiles {q, 31-q} so per-CU work is constant.
  const int qbase = (blockIdx.x + (blockIdx.y & 7)) & 31;
  const int qt = (blockIdx.y & 8) ? (31 - qbase) : qbase;
  const int kvh = h >> 2;
  const int q0 = qt * 64;
  const int last = 2 * qt + 1;
  const int wu = __builtin_amdgcn_readfirstlane(w);
  u16* pwv = &Pw[w * 512];
  constexpr float L2E = 1.4426950408889634f;

  // Q fragments (B-operand: col q = lm, contiguous k)
  bf16x8 qf[4];
  {
    size_t r0 = (size_t)(b * TT + q0 + w * 16 + lm) * NKV + h * HDIM;
    #pragma unroll
    for (int ks = 0; ks < 4; ++ks)
      qf[ks] = *(const bf16x8*)(QKV + r0 + ks * 32 + quad * 8);
  }

  f32x4 o[8];
  #pragma unroll
  for (int i = 0; i < 8; ++i) o[i] = (f32x4){0.f, 0.f, 0.f, 0.f};
  float m_ = -1e30f, l_ = 0.f;

  // hoisted per-thread staging pointers (advance by one 32-row tile per stage)
  const u16 *kg[2], *vg[2];
  int koff[2], voff[2];
  #pragma unroll
  for (int i = 0; i < 2; ++i) {
    int p0 = (wu * 2 + i) * 64, p = p0 + l;
    int krow = p >> 4, kcp = p & 15, kcl = kcp ^ (krow & 15);
    kg[i] = QKV + (size_t)(b * TT + krow) * NKV + 2048 + kvh * HDIM + kcl * 8;
    koff[i] = p0 * 8;
    int vd = p >> 2, vcp = p & 3, vcl = vcp ^ (vd & 3);
    vg[i] = Vt + (size_t)((b * KVHN + kvh) * HDIM + vd) * TT + vcl * 8;
    voff[i] = p0 * 8;
  }

  // prologue: stage tile 0 into A buffers
  #pragma unroll
  for (int i = 0; i < 2; ++i) {
    dma16(kg[i], KsA + koff[i]);
    dma16(vg[i], VsA + voff[i]);
    kg[i] += 32 * NKV;
    vg[i] += 32;
  }

  const int qrow = q0 + w * 16 + lm;

  auto body = [&](int kt, const u16* kcur, const u16* vcur, u16* knx, u16* vnx) {
    __syncthreads();                       // cur buffers landed; prev reads done
    const bool pf = kt < last;
    if (pf) {
      #pragma unroll
      for (int i = 0; i < 2; ++i) dma16(vg[i], vnx + voff[i]);
    }

    // S^T = K . Q^T
    f32x4 s[2];
    s[0] = (f32x4){0.f, 0.f, 0.f, 0.f};
    s[1] = (f32x4){0.f, 0.f, 0.f, 0.f};
    __builtin_amdgcn_s_setprio(1);
    #pragma unroll
    for (int ks = 0; ks < 4; ++ks) {
      #pragma unroll
      for (int mt = 0; mt < 2; ++mt) {
        bf16x8 kb = *(const bf16x8*)&kcur[(mt * 16 + lm) * 128 + (((ks * 4 + quad) ^ lm) * 8)];
        s[mt] = __builtin_amdgcn_mfma_f32_16x16x32_bf16(kb, qf[ks], s[mt], 0, 0, 0);
      }
    }
    __builtin_amdgcn_s_setprio(0);
    if (pf) {
      #pragma unroll
      for (int i = 0; i < 2; ++i) {
        dma16(kg[i], knx + koff[i]);
        kg[i] += 32 * NKV;
        vg[i] += 32;
      }
    }

    // causal mask on diagonal tiles
    if (kt >= 2 * qt) {
      #pragma unroll
      for (int mt = 0; mt < 2; ++mt)
        #pragma unroll
        for (int r = 0; r < 4; ++r) {
          int kv = kt * 32 + mt * 16 + quad * 4 + r;
          if (kv > qrow) s[mt][r] = -1e30f;
        }
    }

    // online softmax with defer-max (THR=8): keep old max while the tile max
    // hasn't grown by >8 -> skip rescale, P bounded by e^8 (bf16-safe).
    float mx = -1e30f;
    #pragma unroll
    for (int mt = 0; mt < 2; ++mt)
      #pragma unroll
      for (int r = 0; r < 4; ++r) mx = fmaxf(mx, s[mt][r]);
    mx = fmaxf(mx, __shfl_xor(mx, 16));
    mx = fmaxf(mx, __shfl_xor(mx, 32));
    bool upd = mx > m_ + 8.f;
    float mn = upd ? mx : m_;
    float al = upd ? exp2f((m_ - mn) * L2E) : 1.f;
    m_ = mn;
    float sum = 0.f;
    #pragma unroll
    for (int mt = 0; mt < 2; ++mt)
      #pragma unroll
      for (int r = 0; r < 4; ++r) {
        float pv = exp2f((s[mt][r] - mn) * L2E);
        s[mt][r] = pv;
        sum += pv;
      }
    sum += __shfl_xor(sum, 16);
    sum += __shfl_xor(sum, 32);
    l_ = l_ * al + sum;

    // P -> LDS (b64 swizzled), per-wave region
    #pragma unroll
    for (int mt = 0; mt < 2; ++mt) {
      u32 p01 = pack2(s[mt][0], s[mt][1]);
      u32 p23 = pack2(s[mt][2], s[mt][3]);
      int phys = (mt * 2 + (quad >> 1)) ^ (lm & 3);
      int addr = lm * 32 + phys * 8 + (quad & 1) * 4;
      uint2 uv; uv.x = p01; uv.y = p23;
      *(uint2*)&pwv[addr] = uv;
    }
    if (__any(upd)) {
      #pragma unroll
      for (int i = 0; i < 8; ++i)
        #pragma unroll
        for (int r = 0; r < 4; ++r) o[i][r] *= al;
    }

    // O^T += V^T . P^T
    int coff = (quad ^ (lm & 3)) * 8;
    bf16x8 pb = *(const bf16x8*)&pwv[lm * 32 + coff];
    __builtin_amdgcn_s_setprio(1);
    #pragma unroll
    for (int mt2 = 0; mt2 < 8; ++mt2) {
      bf16x8 vb = *(const bf16x8*)&vcur[(mt2 * 16 + lm) * 32 + coff];
      o[mt2] = __builtin_amdgcn_mfma_f32_16x16x32_bf16(vb, pb, o[mt2], 0, 0, 0);
    }
    __builtin_amdgcn_s_setprio(0);
  };

  for (int kt = 0; kt <= last; ++kt) {
    if ((kt & 1) == 0) body(kt, KsA, VsA, KsB, VsB);
    else               body(kt, KsB, VsB, KsA, VsA);
  }

  // epilogue: O^T -> LDS transpose (reuse dead K buffers) -> coalesced stores
  __syncthreads();   // all waves past their last K/V reads
  u16* esc = ((w & 2) ? KsB : KsA) + (w & 1) * 2048;
  float inv = 1.f / l_;
  #pragma unroll
  for (int mt2 = 0; mt2 < 8; ++mt2) {
    u32 a0 = pack2(o[mt2][0] * inv, o[mt2][1] * inv);
    u32 a1 = pack2(o[mt2][2] * inv, o[mt2][3] * inv);
    int phys = (mt2 * 2 + (quad >> 1)) ^ (lm & 7);
    int addr = lm * 128 + phys * 8 + (quad & 1) * 4;
    uint2 uv; uv.x = a0; uv.y = a1;
    *(uint2*)&esc[addr] = uv;
  }
  #pragma unroll
  for (int i = 0; i < 4; ++i) {
    int p = i * 64 + l;
    int row = p >> 4, cl = p & 15;
    int cph = cl ^ (row & 7);
    uint4 val = *(const uint4*)&esc[row * 128 + cph * 8];
    *(uint4*)(Ob + (size_t)(b * TT + q0 + w * 16 + row) * DD + h * HDIM + cl * 8) = val;
  }
}

extern "C" void kernel_launch(void* const* d_in, const int* in_sizes, int n_in,
                              void* d_out, int out_size, void* d_ws, size_t ws_size,
                              hipStream_t stream) {
  const float* x  = (const float*)d_in[0];
  const float* Wq = (const float*)d_in[1];
  const float* Wk = (const float*)d_in[2];
  const float* Wv = (const float*)d_in[3];
  const float* Wo = (const float*)d_in[4];
  float* out = (float*)d_out;

  // ws (u16 elems): xb @0 (8M, -> Ob) | WqkvT @8M (6M, -> Vt) | WoT @14.68M (4M)
  u16* xb    = (u16*)d_ws;
  u16* WqkvT = xb + 8388608;
  u16* WoT   = xb + 14680064;
  u16* Vt    = WqkvT;               // alias, live after QKV GEMM
  u16* Ob    = xb;                  // alias, live after QKV GEMM
  u16* QKVb  = (u16*)d_out;         // bf16 [4096][3072] in the 32MB out buffer

  dim3 blk(256);
  castf2b<<<8192, blk, 0, stream>>>(x, xb);
  tcast<<<dim3(64, 64), blk, 0, stream>>>(Wq, WqkvT, DD, DD);
  tcast<<<dim3(16, 64), blk, 0, stream>>>(Wk, WqkvT + (size_t)2048 * DD, DD, 512);
  tcast<<<dim3(16, 64), blk, 0, stream>>>(Wv, WqkvT + (size_t)2560 * DD, DD, 512);
  tcast<<<dim3(64, 64), blk, 0, stream>>>(Wo, WoT, DD, DD);

  gemm2<1><<<dim3(NKV / 128, 32), blk, 0, stream>>>(xb, WqkvT, QKVb, NKV, DD);
  rope2<<<BB * TT, blk, 0, stream>>>(QKVb);
  vtrans<<<dim3(32, 8, BB), blk, 0, stream>>>(QKVb, Vt);
  attn3<<<dim3(32, HH, BB), blk, 0, stream>>>(QKVb, Vt, Ob);
  gemm2<0><<<dim3(DD / 128, 32), blk, 0, stream>>>(Ob, WoT, out, DD, DD);
}

// Round 2
// 334.972 us; speedup vs baseline: 1.0245x; 1.0245x over previous
//
#include <hip/hip_runtime.h>
#include <math.h>

#define BB 2
#define TT 2048
#define DD 2048
#define HH 16
#define KVHN 4
#define HDIM 128
#define NKV 3072   // packed q|k|v row width

typedef unsigned short u16;
typedef unsigned int u32;
typedef __bf16 bf16x8 __attribute__((ext_vector_type(8)));
typedef float  f32x4  __attribute__((ext_vector_type(4)));

#define AS1 __attribute__((address_space(1)))
#define AS3 __attribute__((address_space(3)))

__device__ __forceinline__ void dma16(const u16* g, u16* l) {
  __builtin_amdgcn_global_load_lds((const AS1 u32*)g, (AS3 u32*)l, 16, 0, 0);
}

__device__ __forceinline__ u16 f2bf(float f) {
  u32 u = __float_as_uint(f);
  u32 r = (u + 0x7FFFu + ((u >> 16) & 1u)) >> 16;
  return (u16)r;
}
__device__ __forceinline__ float bf2f(u32 h) { return __uint_as_float(h << 16); }

__device__ __forceinline__ u32 pack2(float a, float b) {
  union { __bf16 h[2]; u32 u; } cv;
  cv.h[0] = (__bf16)a; cv.h[1] = (__bf16)b;
  return cv.u;
}

// ---------------- cast fp32 -> bf16 ----------------------------------------
__global__ __launch_bounds__(256) void castf2b(const float* __restrict__ in,
                                               u16* __restrict__ out) {
  size_t i4 = (size_t)blockIdx.x * 256 + threadIdx.x;
  float4 v = *(const float4*)(in + i4 * 4);
  ushort4 o;
  o.x = f2bf(v.x); o.y = f2bf(v.y); o.z = f2bf(v.z); o.w = f2bf(v.w);
  *(ushort4*)(out + i4 * 4) = o;
}

// ---------------- transpose + cast: W[K][N] fp32 -> WT[N][K] bf16 ----------
__global__ __launch_bounds__(256) void tcast(const float* __restrict__ W,
                                             u16* __restrict__ WT,
                                             int K, int N) {
  __shared__ float tile[32][33];
  const int n0 = blockIdx.x * 32, k0 = blockIdx.y * 32;
  const int r = threadIdx.x >> 3;
  const int c4 = (threadIdx.x & 7) * 4;
  float4 v = *(const float4*)(W + (size_t)(k0 + r) * N + n0 + c4);
  tile[r][c4 + 0] = v.x; tile[r][c4 + 1] = v.y;
  tile[r][c4 + 2] = v.z; tile[r][c4 + 3] = v.w;
  __syncthreads();
  ushort4 o;
  o.x = f2bf(tile[c4 + 0][r]); o.y = f2bf(tile[c4 + 1][r]);
  o.z = f2bf(tile[c4 + 2][r]); o.w = f2bf(tile[c4 + 3][r]);
  *(ushort4*)(WT + (size_t)(n0 + r) * K + k0 + c4) = o;
}

// ---------------- m97-style MFMA GEMM: C = A @ BT^T ------------------------
template <int OUT_BF16>
__global__ __launch_bounds__(256) void gemm2(const u16* __restrict__ A,
                                             const u16* __restrict__ BT,
                                             void* __restrict__ Cv,
                                             int N, int K) {
  __shared__ u16 As[128 * 32];
  __shared__ u16 Bs[128 * 32];
  const int t = threadIdx.x;
  const int l = t & 63, w = t >> 6;
  const int lm = l & 15, quad = l >> 4;
  const int wm = w & 1, wn = w >> 1;
  const int m0 = blockIdx.y * 128, n0 = blockIdx.x * 128;
  const int wu = __builtin_amdgcn_readfirstlane(w);

  f32x4 acc[4][4];
  #pragma unroll
  for (int i = 0; i < 4; ++i)
    #pragma unroll
    for (int j = 0; j < 4; ++j) acc[i][j] = (f32x4){0.f, 0.f, 0.f, 0.f};

  for (int k0 = 0; k0 < K; k0 += 32) {
    __syncthreads();
    #pragma unroll
    for (int i = 0; i < 2; ++i) {
      int p0 = (wu * 2 + i) * 64;
      int p = p0 + l;
      int row = p >> 2, c = p & 3;
      dma16(A  + (size_t)(m0 + row) * K + k0 + c * 8, &As[p0 * 8]);
      dma16(BT + (size_t)(n0 + row) * K + k0 + c * 8, &Bs[p0 * 8]);
    }
    __syncthreads();
    bf16x8 a[4], bq[4];
    #pragma unroll
    for (int i = 0; i < 4; ++i)
      a[i] = *(const bf16x8*)&As[(wm * 64 + i * 16 + lm) * 32 + quad * 8];
    #pragma unroll
    for (int j = 0; j < 4; ++j)
      bq[j] = *(const bf16x8*)&Bs[(wn * 64 + j * 16 + lm) * 32 + quad * 8];
    #pragma unroll
    for (int i = 0; i < 4; ++i)
      #pragma unroll
      for (int j = 0; j < 4; ++j)
        acc[i][j] = __builtin_amdgcn_mfma_f32_16x16x32_bf16(a[i], bq[j], acc[i][j], 0, 0, 0);
  }

  #pragma unroll
  for (int i = 0; i < 4; ++i) {
    #pragma unroll
    for (int r = 0; r < 4; ++r) {
      size_t gr = (size_t)(m0 + wm * 64 + i * 16 + quad * 4 + r);
      #pragma unroll
      for (int j = 0; j < 4; ++j) {
        int gc = n0 + wn * 64 + j * 16 + lm;
        if (OUT_BF16) ((u16*)Cv)[gr * N + gc] = f2bf(acc[i][j][r]);
        else          ((float*)Cv)[gr * N + gc] = acc[i][j][r];
      }
    }
  }
}

// ---------------- RoPE in-place on packed QKV rows (q scaled) --------------
__global__ __launch_bounds__(256) void rope2(u16* p) {
  const int row = blockIdx.x;
  const int pos = row & (TT - 1);
  u16* base = p + (size_t)row * NKV;
  float e0[5], e1[5];
  #pragma unroll
  for (int i = 0; i < 5; ++i) {
    int item = threadIdx.x + i * 256;
    int h20 = item >> 6, f = item & 63;
    int col = (h20 < 16) ? h20 * 128 : 2048 + (h20 - 16) * 128;
    u32 u = *(const u32*)(base + col + 2 * f);
    e0[i] = bf2f(u & 0xffffu);
    e1[i] = bf2f(u >> 16);
  }
  __syncthreads();
  #pragma unroll
  for (int i = 0; i < 5; ++i) {
    int item = threadIdx.x + i * 256;
    int h20 = item >> 6, f = item & 63;
    int col = (h20 < 16) ? h20 * 128 : 2048 + (h20 - 16) * 128;
    float sc = (h20 < 16) ? 0.08838834764831845f : 1.0f;
    float inv = exp2f((float)f * -0.20762050593046898f);  // 10000^(-f/64)
    float ang = (float)pos * inv;
    float sn, cs;
    sincosf(ang, &sn, &cs);
    base[col + f]      = f2bf((e0[i] * cs - e1[i] * sn) * sc);
    base[col + 64 + f] = f2bf((e0[i] * sn + e1[i] * cs) * sc);
  }
}

// ---------------- V transpose: QKV v-part -> Vt[(b*4+vh)*128+d][T] ---------
__global__ __launch_bounds__(256) void vtrans(const u16* __restrict__ QKV,
                                              u16* __restrict__ Vt) {
  __shared__ u16 tl[64][72];
  const int t0 = blockIdx.x * 64;
  const int y  = blockIdx.y;        // 0..7
  const int b  = blockIdx.z;
  #pragma unroll
  for (int i = 0; i < 2; ++i) {
    int idx = threadIdx.x + i * 256;
    int r = idx >> 3, c = (idx & 7) * 8;
    *(uint4*)&tl[r][c] =
        *(const uint4*)(QKV + (size_t)(b * TT + t0 + r) * NKV + 2560 + y * 64 + c);
  }
  __syncthreads();
  const int vh = y >> 1;
  #pragma unroll
  for (int i = 0; i < 2; ++i) {
    int idx = threadIdx.x + i * 256;
    int dr = idx >> 3, tc = (idx & 7) * 8;
    u16 tmp[8];
    #pragma unroll
    for (int j = 0; j < 8; ++j) tmp[j] = tl[tc + j][dr];
    int dloc = (y & 1) * 64 + dr;
    *(uint4*)(Vt + (size_t)((b * KVHN + vh) * HDIM + dloc) * TT + t0 + tc) =
        *(const uint4*)tmp;
  }
}

// ---------------- MFMA flash attention v4 ----------------------------------
// KVBLK=32, 4 blocks/CU.  Bank-conflict-free LDS geometry:
//  K: [32][128] rows (256B) with 16-chunk XOR (unchanged, 2-way max).
//  V: [64][64] rows (128B): row r packs (d=r, t0..31) and (d=r+64, t0..31),
//     8-chunk XOR, permutation applied on the GLOBAL source (linear LDS dst).
//  P: [8][64] rows (128B): row r packs q=2r and q=2r+1, 8-slot XOR.
__global__ __launch_bounds__(256, 4) void attn4(const u16* __restrict__ QKV,
                                                const u16* __restrict__ Vt,
                                                u16* __restrict__ Ob) {
  __shared__ u16 KsA[32 * 128], KsB[32 * 128];
  __shared__ u16 VsA[64 * 64], VsB[64 * 64];
  __shared__ u16 Pw[4 * 512];
  const int t = threadIdx.x;
  const int l = t & 63, w = t >> 6;
  const int lm = l & 15, quad = l >> 4;
  const int h = blockIdx.y, b = blockIdx.z;
  // complement-pair qt swizzle: blocks (x,y) and (x,y+8) share a CU (ids
  // differ by 256); give them q-tiles {q, 31-q} so per-CU work is constant.
  const int qbase = (blockIdx.x + (blockIdx.y & 7)) & 31;
  const int qt = (blockIdx.y & 8) ? (31 - qbase) : qbase;
  const int kvh = h >> 2;
  const int q0 = qt * 64;
  const int last = 2 * qt + 1;
  const int wu = __builtin_amdgcn_readfirstlane(w);
  u16* pwv = &Pw[w * 512];
  constexpr float L2E = 1.4426950408889634f;

  // Q fragments (B-operand: col q = lm, contiguous k)
  bf16x8 qf[4];
  {
    size_t r0 = (size_t)(b * TT + q0 + w * 16 + lm) * NKV + h * HDIM;
    #pragma unroll
    for (int ks = 0; ks < 4; ++ks)
      qf[ks] = *(const bf16x8*)(QKV + r0 + ks * 32 + quad * 8);
  }

  f32x4 o[8];
  #pragma unroll
  for (int i = 0; i < 8; ++i) o[i] = (f32x4){0.f, 0.f, 0.f, 0.f};
  float m_ = -1e30f, l_ = 0.f;

  // hoisted per-thread staging pointers (advance by one 32-row tile per stage)
  const u16 *kg[2], *vg[2];
  int koff[2], voff[2];
  #pragma unroll
  for (int i = 0; i < 2; ++i) {
    int p0 = (wu * 2 + i) * 64, p = p0 + l;
    // K: LDS chunk p = (row, phys), logical chunk = phys ^ (row & 15)
    int krow = p >> 4, kcp = p & 15, kcl = kcp ^ (krow & 15);
    kg[i] = QKV + (size_t)(b * TT + krow) * NKV + 2048 + kvh * HDIM + kcl * 8;
    koff[i] = p0 * 8;
    // V: LDS chunk p = (row, phys), c_log = phys ^ (row&7);
    //    c_log<4 -> d=row, tch=c_log; c_log>=4 -> d=row+64, tch=c_log-4.
    int vrow = p >> 3, vphys = p & 7, vcl = vphys ^ (vrow & 7);
    int vd = vrow + (vcl >> 2) * 64, vtch = vcl & 3;
    vg[i] = Vt + (size_t)((b * KVHN + kvh) * HDIM + vd) * TT + vtch * 8;
    voff[i] = p0 * 8;
  }

  // prologue: stage tile 0 into A buffers
  #pragma unroll
  for (int i = 0; i < 2; ++i) {
    dma16(kg[i], KsA + koff[i]);
    dma16(vg[i], VsA + voff[i]);
    kg[i] += 32 * NKV;
    vg[i] += 32;
  }

  const int qrow = q0 + w * 16 + lm;

  auto body = [&](int kt, const u16* kcur, const u16* vcur, u16* knx, u16* vnx) {
    __syncthreads();                       // cur buffers landed; prev reads done
    const bool pf = kt < last;
    if (pf) {
      #pragma unroll
      for (int i = 0; i < 2; ++i) dma16(vg[i], vnx + voff[i]);
    }

    // S^T = K . Q^T
    f32x4 s[2];
    s[0] = (f32x4){0.f, 0.f, 0.f, 0.f};
    s[1] = (f32x4){0.f, 0.f, 0.f, 0.f};
    __builtin_amdgcn_s_setprio(1);
    #pragma unroll
    for (int ks = 0; ks < 4; ++ks) {
      #pragma unroll
      for (int mt = 0; mt < 2; ++mt) {
        bf16x8 kb = *(const bf16x8*)&kcur[(mt * 16 + lm) * 128 + (((ks * 4 + quad) ^ lm) * 8)];
        s[mt] = __builtin_amdgcn_mfma_f32_16x16x32_bf16(kb, qf[ks], s[mt], 0, 0, 0);
      }
    }
    __builtin_amdgcn_s_setprio(0);
    if (pf) {
      #pragma unroll
      for (int i = 0; i < 2; ++i) {
        dma16(kg[i], knx + koff[i]);
        kg[i] += 32 * NKV;
        vg[i] += 32;
      }
    }

    // causal mask on diagonal tiles
    if (kt >= 2 * qt) {
      #pragma unroll
      for (int mt = 0; mt < 2; ++mt)
        #pragma unroll
        for (int r = 0; r < 4; ++r) {
          int kv = kt * 32 + mt * 16 + quad * 4 + r;
          if (kv > qrow) s[mt][r] = -1e30f;
        }
    }

    // online softmax with defer-max (THR=8)
    float mx = -1e30f;
    #pragma unroll
    for (int mt = 0; mt < 2; ++mt)
      #pragma unroll
      for (int r = 0; r < 4; ++r) mx = fmaxf(mx, s[mt][r]);
    mx = fmaxf(mx, __shfl_xor(mx, 16));
    mx = fmaxf(mx, __shfl_xor(mx, 32));
    bool upd = mx > m_ + 8.f;
    float mn = upd ? mx : m_;
    float al = upd ? exp2f((m_ - mn) * L2E) : 1.f;
    m_ = mn;
    float sum = 0.f;
    #pragma unroll
    for (int mt = 0; mt < 2; ++mt)
      #pragma unroll
      for (int r = 0; r < 4; ++r) {
        float pv = exp2f((s[mt][r] - mn) * L2E);
        s[mt][r] = pv;
        sum += pv;
      }
    sum += __shfl_xor(sum, 16);
    sum += __shfl_xor(sum, 32);
    l_ = l_ * al + sum;

    // P -> LDS: row = lm>>1 (128B rows, q-pairs), slot XOR over 8 chunks.
    // lane holds P^T[kv = mt*16 + quad*4 + r][q = lm]; kv chunk c = mt*2+(quad>>1).
    #pragma unroll
    for (int mt = 0; mt < 2; ++mt) {
      u32 p01 = pack2(s[mt][0], s[mt][1]);
      u32 p23 = pack2(s[mt][2], s[mt][3]);
      int c = mt * 2 + (quad >> 1);
      int addr = (lm >> 1) * 64 + ((lm & 1) * 4 + (c ^ ((lm >> 1) & 3))) * 8 + (quad & 1) * 4;
      uint2 uv; uv.x = p01; uv.y = p23;
      *(uint2*)&pwv[addr] = uv;
    }
    if (__any(upd)) {
      #pragma unroll
      for (int i = 0; i < 8; ++i)
        #pragma unroll
        for (int r = 0; r < 4; ++r) o[i][r] *= al;
    }

    // O^T += V^T . P^T
    int paddr = (lm >> 1) * 64 + ((lm & 1) * 4 + (quad ^ ((lm >> 1) & 3))) * 8;
    bf16x8 pb = *(const bf16x8*)&pwv[paddr];
    __builtin_amdgcn_s_setprio(1);
    #pragma unroll
    for (int mt2 = 0; mt2 < 8; ++mt2) {
      int vrow = (mt2 & 3) * 16 + lm;                    // d & 63
      int vphys = ((mt2 >> 2) * 4 + quad) ^ (vrow & 7);  // c_log ^ (row&7)
      bf16x8 vb = *(const bf16x8*)&vcur[vrow * 64 + vphys * 8];
      o[mt2] = __builtin_amdgcn_mfma_f32_16x16x32_bf16(vb, pb, o[mt2], 0, 0, 0);
    }
    __builtin_amdgcn_s_setprio(0);
  };

  for (int kt = 0; kt <= last; ++kt) {
    if ((kt & 1) == 0) body(kt, KsA, VsA, KsB, VsB);
    else               body(kt, KsB, VsB, KsA, VsA);
  }

  // epilogue: O^T -> LDS transpose (reuse dead K buffers) -> coalesced stores
  __syncthreads();   // all waves past their last K/V reads
  u16* esc = ((w & 2) ? KsB : KsA) + (w & 1) * 2048;
  float inv = 1.f / l_;
  #pragma unroll
  for (int mt2 = 0; mt2 < 8; ++mt2) {
    u32 a0 = pack2(o[mt2][0] * inv, o[mt2][1] * inv);
    u32 a1 = pack2(o[mt2][2] * inv, o[mt2][3] * inv);
    int phys = (mt2 * 2 + (quad >> 1)) ^ (lm & 7);
    int addr = lm * 128 + phys * 8 + (quad & 1) * 4;
    uint2 uv; uv.x = a0; uv.y = a1;
    *(uint2*)&esc[addr] = uv;
  }
  #pragma unroll
  for (int i = 0; i < 4; ++i) {
    int p = i * 64 + l;
    int row = p >> 4, cl = p & 15;
    int cph = cl ^ (row & 7);
    uint4 val = *(const uint4*)&esc[row * 128 + cph * 8];
    *(uint4*)(Ob + (size_t)(b * TT + q0 + w * 16 + row) * DD + h * HDIM + cl * 8) = val;
  }
}

extern "C" void kernel_launch(void* const* d_in, const int* in_sizes, int n_in,
                              void* d_out, int out_size, void* d_ws, size_t ws_size,
                              hipStream_t stream) {
  const float* x  = (const float*)d_in[0];
  const float* Wq = (const float*)d_in[1];
  const float* Wk = (const float*)d_in[2];
  const float* Wv = (const float*)d_in[3];
  const float* Wo = (const float*)d_in[4];
  float* out = (float*)d_out;

  // ws (u16 elems): xb @0 (8M, -> Ob) | WqkvT @8M (6M, -> Vt) | WoT @14.68M (4M)
  u16* xb    = (u16*)d_ws;
  u16* WqkvT = xb + 8388608;
  u16* WoT   = xb + 14680064;
  u16* Vt    = WqkvT;               // alias, live after QKV GEMM
  u16* Ob    = xb;                  // alias, live after QKV GEMM
  u16* QKVb  = (u16*)d_out;         // bf16 [4096][3072] in the 32MB out buffer

  dim3 blk(256);
  castf2b<<<8192, blk, 0, stream>>>(x, xb);
  tcast<<<dim3(64, 64), blk, 0, stream>>>(Wq, WqkvT, DD, DD);
  tcast<<<dim3(16, 64), blk, 0, stream>>>(Wk, WqkvT + (size_t)2048 * DD, DD, 512);
  tcast<<<dim3(16, 64), blk, 0, stream>>>(Wv, WqkvT + (size_t)2560 * DD, DD, 512);
  tcast<<<dim3(64, 64), blk, 0, stream>>>(Wo, WoT, DD, DD);

  gemm2<1><<<dim3(NKV / 128, 32), blk, 0, stream>>>(xb, WqkvT, QKVb, NKV, DD);
  rope2<<<BB * TT, blk, 0, stream>>>(QKVb);
  vtrans<<<dim3(32, 8, BB), blk, 0, stream>>>(QKVb, Vt);
  attn4<<<dim3(32, HH, BB), blk, 0, stream>>>(QKVb, Vt, Ob);
  gemm2<0><<<dim3(DD / 128, 32), blk, 0, stream>>>(Ob, WoT, out, DD, DD);
}

// Round 3
// 326.367 us; speedup vs baseline: 1.0515x; 1.0264x over previous
//
#include <hip/hip_runtime.h>
#include <math.h>

#define BB 2
#define TT 2048
#define DD 2048
#define HH 16
#define KVHN 4
#define HDIM 128
#define NKV 3072   // packed q|k|v row width

typedef unsigned short u16;
typedef unsigned int u32;
typedef __bf16 bf16x8 __attribute__((ext_vector_type(8)));
typedef float  f32x4  __attribute__((ext_vector_type(4)));

#define AS1 __attribute__((address_space(1)))
#define AS3 __attribute__((address_space(3)))

__device__ __forceinline__ void dma16(const u16* g, u16* l) {
  __builtin_amdgcn_global_load_lds((const AS1 u32*)g, (AS3 u32*)l, 16, 0, 0);
}

__device__ __forceinline__ u16 f2bf(float f) {
  u32 u = __float_as_uint(f);
  u32 r = (u + 0x7FFFu + ((u >> 16) & 1u)) >> 16;
  return (u16)r;
}
__device__ __forceinline__ float bf2f(u32 h) { return __uint_as_float(h << 16); }

__device__ __forceinline__ u32 pack2(float a, float b) {
  union { __bf16 h[2]; u32 u; } cv;
  cv.h[0] = (__bf16)a; cv.h[1] = (__bf16)b;
  return cv.u;
}

// ---------------- cast fp32 -> bf16 ----------------------------------------
__global__ __launch_bounds__(256) void castf2b(const float* __restrict__ in,
                                               u16* __restrict__ out) {
  size_t i4 = (size_t)blockIdx.x * 256 + threadIdx.x;
  float4 v = *(const float4*)(in + i4 * 4);
  ushort4 o;
  o.x = f2bf(v.x); o.y = f2bf(v.y); o.z = f2bf(v.z); o.w = f2bf(v.w);
  *(ushort4*)(out + i4 * 4) = o;
}

// ---------------- transpose + cast: W[K][N] fp32 -> WT[N][K] bf16 ----------
__global__ __launch_bounds__(256) void tcast(const float* __restrict__ W,
                                             u16* __restrict__ WT,
                                             int K, int N) {
  __shared__ float tile[32][33];
  const int n0 = blockIdx.x * 32, k0 = blockIdx.y * 32;
  const int r = threadIdx.x >> 3;
  const int c4 = (threadIdx.x & 7) * 4;
  float4 v = *(const float4*)(W + (size_t)(k0 + r) * N + n0 + c4);
  tile[r][c4 + 0] = v.x; tile[r][c4 + 1] = v.y;
  tile[r][c4 + 2] = v.z; tile[r][c4 + 3] = v.w;
  __syncthreads();
  ushort4 o;
  o.x = f2bf(tile[c4 + 0][r]); o.y = f2bf(tile[c4 + 1][r]);
  o.z = f2bf(tile[c4 + 2][r]); o.w = f2bf(tile[c4 + 3][r]);
  *(ushort4*)(WT + (size_t)(n0 + r) * K + k0 + c4) = o;
}

// ---------------- 8-phase-style counted-vmcnt MFMA GEMM --------------------
// C = A @ BT^T.  BM=128, BN=256, BK=64, 512 thr = 8 waves (2M x 4N).
// Tri-buffered LDS (3 x 48KB), raw s_barrier + counted s_waitcnt vmcnt(N)
// so prefetch DMAs stay in flight across barriers (T3+T4).  LDS rows are
// 128B with 8-chunk XOR swizzle; permutation applied on the GLOBAL source
// (linear LDS dest, both-sides-or-neither) and on the ds_read chunk index.
template <int OUT_BF16>
__global__ __launch_bounds__(512) void gemm8p(const u16* __restrict__ A,
                                              const u16* __restrict__ BT,
                                              void* __restrict__ Cv,
                                              int N, int K) {
  __shared__ u16 lds[3 * 24576];   // per buffer: A 128x64 (8192) | B 256x64 (16384)
  const int t = threadIdx.x;
  const int l = t & 63, w = t >> 6;
  const int lm = l & 15, quad = l >> 4;
  const int wm = w & 1, wn = w >> 1;
  const int m0 = blockIdx.y * 128, n0 = blockIdx.x * 256;
  const int wu = __builtin_amdgcn_readfirstlane(w);

  // staging source pointers (pre-swizzled global col) + uniform LDS dests
  const u16* srcA[2]; int dstA[2];
  const u16* srcB[4]; int dstB[4];
  #pragma unroll
  for (int i = 0; i < 2; ++i) {
    int p0 = (wu * 2 + i) * 64, p = p0 + l;
    int row = p >> 3, c = (p & 7) ^ (row & 7);
    srcA[i] = A + (size_t)(m0 + row) * K + c * 8;
    dstA[i] = p0 * 8;
  }
  #pragma unroll
  for (int i = 0; i < 4; ++i) {
    int p0 = (wu * 4 + i) * 64, p = p0 + l;
    int row = p >> 3, c = (p & 7) ^ (row & 7);
    srcB[i] = BT + (size_t)(n0 + row) * K + c * 8;
    dstB[i] = 8192 + p0 * 8;
  }

  f32x4 acc[4][4];
  #pragma unroll
  for (int i = 0; i < 4; ++i)
    #pragma unroll
    for (int j = 0; j < 4; ++j) acc[i][j] = (f32x4){0.f, 0.f, 0.f, 0.f};

  auto stage = [&](int bsel) {
    u16* buf = &lds[bsel * 24576];
    #pragma unroll
    for (int i = 0; i < 2; ++i) { dma16(srcA[i], buf + dstA[i]); srcA[i] += 64; }
    #pragma unroll
    for (int i = 0; i < 4; ++i) { dma16(srcB[i], buf + dstB[i]); srcB[i] += 64; }
  };

  stage(0); stage(1); stage(2);           // 18 loads in flight (3 K-tiles)

  const int NT = K >> 6;
  int bsel = 0;
  const int xorc = lm & 7;
  for (int tI = 0; tI < NT; ++tI) {
    // tile tI's 6 loads are the oldest outstanding; allow 2 newer tiles in flight
    if (tI + 2 < NT)      asm volatile("s_waitcnt vmcnt(12)" ::: "memory");
    else if (tI + 1 < NT) asm volatile("s_waitcnt vmcnt(6)" ::: "memory");
    else                  asm volatile("s_waitcnt vmcnt(0)" ::: "memory");
    asm volatile("s_barrier" ::: "memory");   // raw: no vmcnt(0) drain

    const u16* Ab = &lds[bsel * 24576];
    const u16* Bb = Ab + 8192;
    bf16x8 a[2][4], b[2][4];
    #pragma unroll
    for (int ks = 0; ks < 2; ++ks) {
      int ch = ((ks * 4 + quad) ^ xorc) * 8;
      #pragma unroll
      for (int i = 0; i < 4; ++i)
        a[ks][i] = *(const bf16x8*)&Ab[(wm * 64 + i * 16 + lm) * 64 + ch];
      #pragma unroll
      for (int j = 0; j < 4; ++j)
        b[ks][j] = *(const bf16x8*)&Bb[(wn * 64 + j * 16 + lm) * 64 + ch];
    }
    __builtin_amdgcn_s_setprio(1);
    #pragma unroll
    for (int ks = 0; ks < 2; ++ks)
      #pragma unroll
      for (int i = 0; i < 4; ++i)
        #pragma unroll
        for (int j = 0; j < 4; ++j)
          acc[i][j] = __builtin_amdgcn_mfma_f32_16x16x32_bf16(a[ks][i], b[ks][j], acc[i][j], 0, 0, 0);
    __builtin_amdgcn_s_setprio(0);
    asm volatile("s_barrier" ::: "memory");   // all waves done reading buf bsel
    if (tI + 3 < NT) stage(bsel);             // overwrite just-freed buffer
    bsel = (bsel == 2) ? 0 : bsel + 1;
  }

  #pragma unroll
  for (int i = 0; i < 4; ++i) {
    #pragma unroll
    for (int r = 0; r < 4; ++r) {
      size_t gr = (size_t)(m0 + wm * 64 + i * 16 + quad * 4 + r);
      #pragma unroll
      for (int j = 0; j < 4; ++j) {
        int gc = n0 + wn * 64 + j * 16 + lm;
        if (OUT_BF16) ((u16*)Cv)[gr * N + gc] = f2bf(acc[i][j][r]);
        else          ((float*)Cv)[gr * N + gc] = acc[i][j][r];
      }
    }
  }
}

// ---------------- RoPE in-place on packed QKV rows (q scaled) --------------
__global__ __launch_bounds__(256) void rope2(u16* p) {
  const int row = blockIdx.x;
  const int pos = row & (TT - 1);
  u16* base = p + (size_t)row * NKV;
  float e0[5], e1[5];
  #pragma unroll
  for (int i = 0; i < 5; ++i) {
    int item = threadIdx.x + i * 256;
    int h20 = item >> 6, f = item & 63;
    int col = (h20 < 16) ? h20 * 128 : 2048 + (h20 - 16) * 128;
    u32 u = *(const u32*)(base + col + 2 * f);
    e0[i] = bf2f(u & 0xffffu);
    e1[i] = bf2f(u >> 16);
  }
  __syncthreads();
  #pragma unroll
  for (int i = 0; i < 5; ++i) {
    int item = threadIdx.x + i * 256;
    int h20 = item >> 6, f = item & 63;
    int col = (h20 < 16) ? h20 * 128 : 2048 + (h20 - 16) * 128;
    float sc = (h20 < 16) ? 0.08838834764831845f : 1.0f;
    float inv = exp2f((float)f * -0.20762050593046898f);  // 10000^(-f/64)
    float ang = (float)pos * inv;
    float sn, cs;
    sincosf(ang, &sn, &cs);
    base[col + f]      = f2bf((e0[i] * cs - e1[i] * sn) * sc);
    base[col + 64 + f] = f2bf((e0[i] * sn + e1[i] * cs) * sc);
  }
}

// ---------------- V transpose: QKV v-part -> Vt[(b*4+vh)*128+d][T] ---------
__global__ __launch_bounds__(256) void vtrans(const u16* __restrict__ QKV,
                                              u16* __restrict__ Vt) {
  __shared__ u16 tl[64][72];
  const int t0 = blockIdx.x * 64;
  const int y  = blockIdx.y;        // 0..7
  const int b  = blockIdx.z;
  #pragma unroll
  for (int i = 0; i < 2; ++i) {
    int idx = threadIdx.x + i * 256;
    int r = idx >> 3, c = (idx & 7) * 8;
    *(uint4*)&tl[r][c] =
        *(const uint4*)(QKV + (size_t)(b * TT + t0 + r) * NKV + 2560 + y * 64 + c);
  }
  __syncthreads();
  const int vh = y >> 1;
  #pragma unroll
  for (int i = 0; i < 2; ++i) {
    int idx = threadIdx.x + i * 256;
    int dr = idx >> 3, tc = (idx & 7) * 8;
    u16 tmp[8];
    #pragma unroll
    for (int j = 0; j < 8; ++j) tmp[j] = tl[tc + j][dr];
    int dloc = (y & 1) * 64 + dr;
    *(uint4*)(Vt + (size_t)((b * KVHN + vh) * HDIM + dloc) * TT + t0 + tc) =
        *(const uint4*)tmp;
  }
}

// ---------------- MFMA flash attention v4 (unchanged from R2) --------------
__global__ __launch_bounds__(256, 4) void attn4(const u16* __restrict__ QKV,
                                                const u16* __restrict__ Vt,
                                                u16* __restrict__ Ob) {
  __shared__ u16 KsA[32 * 128], KsB[32 * 128];
  __shared__ u16 VsA[64 * 64], VsB[64 * 64];
  __shared__ u16 Pw[4 * 512];
  const int t = threadIdx.x;
  const int l = t & 63, w = t >> 6;
  const int lm = l & 15, quad = l >> 4;
  const int h = blockIdx.y, b = blockIdx.z;
  const int qbase = (blockIdx.x + (blockIdx.y & 7)) & 31;
  const int qt = (blockIdx.y & 8) ? (31 - qbase) : qbase;
  const int kvh = h >> 2;
  const int q0 = qt * 64;
  const int last = 2 * qt + 1;
  const int wu = __builtin_amdgcn_readfirstlane(w);
  u16* pwv = &Pw[w * 512];
  constexpr float L2E = 1.4426950408889634f;

  bf16x8 qf[4];
  {
    size_t r0 = (size_t)(b * TT + q0 + w * 16 + lm) * NKV + h * HDIM;
    #pragma unroll
    for (int ks = 0; ks < 4; ++ks)
      qf[ks] = *(const bf16x8*)(QKV + r0 + ks * 32 + quad * 8);
  }

  f32x4 o[8];
  #pragma unroll
  for (int i = 0; i < 8; ++i) o[i] = (f32x4){0.f, 0.f, 0.f, 0.f};
  float m_ = -1e30f, l_ = 0.f;

  const u16 *kg[2], *vg[2];
  int koff[2], voff[2];
  #pragma unroll
  for (int i = 0; i < 2; ++i) {
    int p0 = (wu * 2 + i) * 64, p = p0 + l;
    int krow = p >> 4, kcp = p & 15, kcl = kcp ^ (krow & 15);
    kg[i] = QKV + (size_t)(b * TT + krow) * NKV + 2048 + kvh * HDIM + kcl * 8;
    koff[i] = p0 * 8;
    int vrow = p >> 3, vphys = p & 7, vcl = vphys ^ (vrow & 7);
    int vd = vrow + (vcl >> 2) * 64, vtch = vcl & 3;
    vg[i] = Vt + (size_t)((b * KVHN + kvh) * HDIM + vd) * TT + vtch * 8;
    voff[i] = p0 * 8;
  }

  #pragma unroll
  for (int i = 0; i < 2; ++i) {
    dma16(kg[i], KsA + koff[i]);
    dma16(vg[i], VsA + voff[i]);
    kg[i] += 32 * NKV;
    vg[i] += 32;
  }

  const int qrow = q0 + w * 16 + lm;

  auto body = [&](int kt, const u16* kcur, const u16* vcur, u16* knx, u16* vnx) {
    __syncthreads();
    const bool pf = kt < last;
    if (pf) {
      #pragma unroll
      for (int i = 0; i < 2; ++i) dma16(vg[i], vnx + voff[i]);
    }

    f32x4 s[2];
    s[0] = (f32x4){0.f, 0.f, 0.f, 0.f};
    s[1] = (f32x4){0.f, 0.f, 0.f, 0.f};
    __builtin_amdgcn_s_setprio(1);
    #pragma unroll
    for (int ks = 0; ks < 4; ++ks) {
      #pragma unroll
      for (int mt = 0; mt < 2; ++mt) {
        bf16x8 kb = *(const bf16x8*)&kcur[(mt * 16 + lm) * 128 + (((ks * 4 + quad) ^ lm) * 8)];
        s[mt] = __builtin_amdgcn_mfma_f32_16x16x32_bf16(kb, qf[ks], s[mt], 0, 0, 0);
      }
    }
    __builtin_amdgcn_s_setprio(0);
    if (pf) {
      #pragma unroll
      for (int i = 0; i < 2; ++i) {
        dma16(kg[i], knx + koff[i]);
        kg[i] += 32 * NKV;
        vg[i] += 32;
      }
    }

    if (kt >= 2 * qt) {
      #pragma unroll
      for (int mt = 0; mt < 2; ++mt)
        #pragma unroll
        for (int r = 0; r < 4; ++r) {
          int kv = kt * 32 + mt * 16 + quad * 4 + r;
          if (kv > qrow) s[mt][r] = -1e30f;
        }
    }

    float mx = -1e30f;
    #pragma unroll
    for (int mt = 0; mt < 2; ++mt)
      #pragma unroll
      for (int r = 0; r < 4; ++r) mx = fmaxf(mx, s[mt][r]);
    mx = fmaxf(mx, __shfl_xor(mx, 16));
    mx = fmaxf(mx, __shfl_xor(mx, 32));
    bool upd = mx > m_ + 8.f;
    float mn = upd ? mx : m_;
    float al = upd ? exp2f((m_ - mn) * L2E) : 1.f;
    m_ = mn;
    float sum = 0.f;
    #pragma unroll
    for (int mt = 0; mt < 2; ++mt)
      #pragma unroll
      for (int r = 0; r < 4; ++r) {
        float pv = exp2f((s[mt][r] - mn) * L2E);
        s[mt][r] = pv;
        sum += pv;
      }
    sum += __shfl_xor(sum, 16);
    sum += __shfl_xor(sum, 32);
    l_ = l_ * al + sum;

    #pragma unroll
    for (int mt = 0; mt < 2; ++mt) {
      u32 p01 = pack2(s[mt][0], s[mt][1]);
      u32 p23 = pack2(s[mt][2], s[mt][3]);
      int c = mt * 2 + (quad >> 1);
      int addr = (lm >> 1) * 64 + ((lm & 1) * 4 + (c ^ ((lm >> 1) & 3))) * 8 + (quad & 1) * 4;
      uint2 uv; uv.x = p01; uv.y = p23;
      *(uint2*)&pwv[addr] = uv;
    }
    if (__any(upd)) {
      #pragma unroll
      for (int i = 0; i < 8; ++i)
        #pragma unroll
        for (int r = 0; r < 4; ++r) o[i][r] *= al;
    }

    int paddr = (lm >> 1) * 64 + ((lm & 1) * 4 + (quad ^ ((lm >> 1) & 3))) * 8;
    bf16x8 pb = *(const bf16x8*)&pwv[paddr];
    __builtin_amdgcn_s_setprio(1);
    #pragma unroll
    for (int mt2 = 0; mt2 < 8; ++mt2) {
      int vrow = (mt2 & 3) * 16 + lm;
      int vphys = ((mt2 >> 2) * 4 + quad) ^ (vrow & 7);
      bf16x8 vb = *(const bf16x8*)&vcur[vrow * 64 + vphys * 8];
      o[mt2] = __builtin_amdgcn_mfma_f32_16x16x32_bf16(vb, pb, o[mt2], 0, 0, 0);
    }
    __builtin_amdgcn_s_setprio(0);
  };

  for (int kt = 0; kt <= last; ++kt) {
    if ((kt & 1) == 0) body(kt, KsA, VsA, KsB, VsB);
    else               body(kt, KsB, VsB, KsA, VsA);
  }

  __syncthreads();
  u16* esc = ((w & 2) ? KsB : KsA) + (w & 1) * 2048;
  float inv = 1.f / l_;
  #pragma unroll
  for (int mt2 = 0; mt2 < 8; ++mt2) {
    u32 a0 = pack2(o[mt2][0] * inv, o[mt2][1] * inv);
    u32 a1 = pack2(o[mt2][2] * inv, o[mt2][3] * inv);
    int phys = (mt2 * 2 + (quad >> 1)) ^ (lm & 7);
    int addr = lm * 128 + phys * 8 + (quad & 1) * 4;
    uint2 uv; uv.x = a0; uv.y = a1;
    *(uint2*)&esc[addr] = uv;
  }
  #pragma unroll
  for (int i = 0; i < 4; ++i) {
    int p = i * 64 + l;
    int row = p >> 4, cl = p & 15;
    int cph = cl ^ (row & 7);
    uint4 val = *(const uint4*)&esc[row * 128 + cph * 8];
    *(uint4*)(Ob + (size_t)(b * TT + q0 + w * 16 + row) * DD + h * HDIM + cl * 8) = val;
  }
}

extern "C" void kernel_launch(void* const* d_in, const int* in_sizes, int n_in,
                              void* d_out, int out_size, void* d_ws, size_t ws_size,
                              hipStream_t stream) {
  const float* x  = (const float*)d_in[0];
  const float* Wq = (const float*)d_in[1];
  const float* Wk = (const float*)d_in[2];
  const float* Wv = (const float*)d_in[3];
  const float* Wo = (const float*)d_in[4];
  float* out = (float*)d_out;

  // ws (u16 elems): xb @0 (8M, -> Ob) | WqkvT @8M (6M, -> Vt) | WoT @14.68M (4M)
  u16* xb    = (u16*)d_ws;
  u16* WqkvT = xb + 8388608;
  u16* WoT   = xb + 14680064;
  u16* Vt    = WqkvT;               // alias, live after QKV GEMM
  u16* Ob    = xb;                  // alias, live after QKV GEMM
  u16* QKVb  = (u16*)d_out;         // bf16 [4096][3072] in the 32MB out buffer

  dim3 blk(256);
  castf2b<<<8192, blk, 0, stream>>>(x, xb);
  tcast<<<dim3(64, 64), blk, 0, stream>>>(Wq, WqkvT, DD, DD);
  tcast<<<dim3(16, 64), blk, 0, stream>>>(Wk, WqkvT + (size_t)2048 * DD, DD, 512);
  tcast<<<dim3(16, 64), blk, 0, stream>>>(Wv, WqkvT + (size_t)2560 * DD, DD, 512);
  tcast<<<dim3(64, 64), blk, 0, stream>>>(Wo, WoT, DD, DD);

  gemm8p<1><<<dim3(NKV / 256, 32), dim3(512), 0, stream>>>(xb, WqkvT, QKVb, NKV, DD);
  rope2<<<BB * TT, blk, 0, stream>>>(QKVb);
  vtrans<<<dim3(32, 8, BB), blk, 0, stream>>>(QKVb, Vt);
  attn4<<<dim3(32, HH, BB), blk, 0, stream>>>(QKVb, Vt, Ob);
  gemm8p<0><<<dim3(DD / 256, 32), dim3(512), 0, stream>>>(Ob, WoT, out, DD, DD);
}